// Round 11
// baseline (299.017 us; speedup 1.0000x reference)
//
#include <hip/hip_runtime.h>
#include <math.h>

#define S_LEN 2048
#define D_DIM 1024
#define NH 16
#define HD 64

typedef __attribute__((ext_vector_type(8))) short bf16x8;
typedef __attribute__((ext_vector_type(4))) float f32x4;

#define MFMA(a, b, c) __builtin_amdgcn_mfma_f32_16x16x32_bf16((a), (b), (c), 0, 0, 0)

__device__ __forceinline__ unsigned short f2bf(float x) {
    unsigned int u = __float_as_uint(x);
    u = (u + 0x7FFFu + ((u >> 16) & 1u)) >> 16;  // round-to-nearest-even
    return (unsigned short)u;
}
__device__ __forceinline__ float bf2f(unsigned short b) {
    return __uint_as_float(((unsigned int)b) << 16);
}
__device__ __forceinline__ void gl_lds16(const void* g, void* l) {
    __builtin_amdgcn_global_load_lds((const __attribute__((address_space(1))) unsigned int*)g,
                                     (__attribute__((address_space(3))) unsigned int*)l, 16, 0, 0);
}

// packed f32x2 -> bf16x2 (low = a, high = b).
#if defined(__has_builtin)
#if __has_builtin(__builtin_amdgcn_cvt_pk_bf16_f32)
#define HAVE_CVT_PK_BF16 1
#endif
#endif
__device__ __forceinline__ unsigned pack_bf16(float a, float b) {
#ifdef HAVE_CVT_PK_BF16
    auto r = __builtin_amdgcn_cvt_pk_bf16_f32(a, b);
    unsigned u;
    __builtin_memcpy(&u, &r, 4);
    return u;
#else
    unsigned ua = __float_as_uint(a) + 0x8000u;
    unsigned ub = __float_as_uint(b) + 0x8000u;
    return __builtin_amdgcn_perm(ub, ua, 0x07060302u);
#endif
}

// Packed hi/lo tiled-swizzled layouts for qkv (BK=32 chunks, identity-copy
// global_load_lds, conflict-free-per-quad-phase LDS reads):
//   Xpk  : [mblk=r>>7][kc=k>>5][row=r&127][g=(hl*4+((k>>3)&3))^(r&7)][k&7]
//   Wq/Wk: [head][kc=d>>5][col=e][g=(hl*4+((d>>3)&3))^(e&7)][d&7]
//   Wv   : [head][kc=d>>5][col=e][g=((d>>3)&3)^(e&3)][d&7]
//   Oatt : [mblk][kblk=k>>6][row][g=((k>>3)&7)^(r&7)][k&7]   (64-k tiles)
//   Wo   : [nblk=n>>6][kblk=k>>6][col=n&63][g=((k>>3)&7)^(n&7)][k&7]

// ---------------------------------------------------------------------------
// prep: input split + weight transpose/split into the packed layouts.
// Wq folded scale = 0.125 * log2(e)  -> scores live in exp2 domain.
// ---------------------------------------------------------------------------
__global__ __launch_bounds__(256) void prep(const float* __restrict__ GLO,
                                            const float* __restrict__ LOC,
                                            const float* __restrict__ Wq,
                                            const float* __restrict__ Wk,
                                            const float* __restrict__ Wv,
                                            const float* __restrict__ Wo,
                                            unsigned short* __restrict__ Xpk,
                                            unsigned short* __restrict__ Wqpk,
                                            unsigned short* __restrict__ Wkpk,
                                            unsigned short* __restrict__ Wvpk,
                                            unsigned short* __restrict__ Wot) {
    int idx = blockIdx.x * 256 + threadIdx.x;  // 0 .. 8M-1
    if (idx < (1 << 22)) {
        const float* src = (idx & (1 << 21)) ? LOC : GLO;
        float x = src[idx & ((1 << 21) - 1)];
        int r = idx >> 10;  // 0..4095
        int k = idx & 1023;
        size_t tb = (size_t)(r >> 7) * 262144 + (size_t)(k >> 5) * 8192 + (r & 127) * 64 + (k & 7);
        int kg = (k >> 3) & 3, r7 = r & 7;
        unsigned short h = f2bf(x);
        Xpk[tb + (size_t)((kg ^ r7)) * 8] = h;
        Xpk[tb + (size_t)(((4 + kg) ^ r7)) * 8] = f2bf(x - bf2f(h));
    } else {
        idx -= (1 << 22);
        int sec = idx >> 20;
        int i = idx & 0xFFFFF;
        if (sec < 3) {
            int e = i & 63;  // fastest -> coalesced read
            int d = (i >> 6) & 1023;
            int hh = i >> 16;
            float wv = ((sec == 0) ? Wq : (sec == 1) ? Wk : Wv)[hh * 65536 + d * 64 + e];
            if (sec == 0) {
                wv *= 0.18033688011112042f;  // 0.125 * log2(e)
                size_t tb =
                    (size_t)hh * 131072 + (size_t)(d >> 5) * 4096 + e * 64 + (d & 7);
                int kg = (d >> 3) & 3, e7 = e & 7;
                unsigned short hi = f2bf(wv);
                Wqpk[tb + (size_t)((kg ^ e7)) * 8] = hi;
                Wqpk[tb + (size_t)(((4 + kg) ^ e7)) * 8] = f2bf(wv - bf2f(hi));
            } else if (sec == 1) {
                size_t tb =
                    (size_t)hh * 131072 + (size_t)(d >> 5) * 4096 + e * 64 + (d & 7);
                int kg = (d >> 3) & 3, e7 = e & 7;
                unsigned short hi = f2bf(wv);
                Wkpk[tb + (size_t)((kg ^ e7)) * 8] = hi;
                Wkpk[tb + (size_t)(((4 + kg) ^ e7)) * 8] = f2bf(wv - bf2f(hi));
            } else {
                size_t t = (size_t)hh * 65536 + (size_t)(d >> 5) * 2048 + e * 32 +
                           (size_t)((((d >> 3) & 3) ^ (e & 3))) * 8 + (d & 7);
                Wvpk[t] = f2bf(wv);
            }
        } else {
            int n = i & 1023;  // fastest -> coalesced read of Wo[k*1024+n]
            int k = i >> 10;
            size_t t = (size_t)(n >> 6) * 65536 + (size_t)(k >> 6) * 4096 + (n & 63) * 64 +
                       ((((k >> 3) & 7) ^ (n & 7)) * 8) + (k & 7);
            Wot[t] = f2bf(Wo[k * 1024 + n]);
        }
    }
}

// ---------------------------------------------------------------------------
// qkv_proj: staged-LDS GEMM, DOUBLE-BUFFERED (BK=32, 36 KB/buffer, 72 KB
// total -> 2 blocks/CU).  One barrier per kc; prefetch for kc+1 issued right
// after the barrier, drained at the next one, hidden under 56 MFMA of compute
// (the attn-r8 pipeline pattern; previous qkv drained 72 KB inside every
// barrier pair).  MFMA order per 32-k step identical to before -> bit-same.
// grid: mblk(32) x head(16) = 512 blocks
// ---------------------------------------------------------------------------
__global__ __launch_bounds__(256) void qkv_proj(const unsigned short* __restrict__ Xpk,
                                                const unsigned short* __restrict__ Wqpk,
                                                const unsigned short* __restrict__ Wkpk,
                                                const unsigned short* __restrict__ Wvpk,
                                                unsigned short* __restrict__ Qh,
                                                unsigned short* __restrict__ Ql,
                                                unsigned short* __restrict__ Kh,
                                                unsigned short* __restrict__ Kl,
                                                unsigned short* __restrict__ Vt) {
    // per buffer (shorts): X 8192, Wq 4096, Wk 4096, Wv 2048 = 18432; x2 = 36864
    __shared__ unsigned short lds[36864];
    const int bid = blockIdx.x;
    const int mblk = bid & 31;
    const int head = bid >> 5;
    const int tid = threadIdx.x;
    const int lane = tid & 63;
    const int w = tid >> 6;
    const int l15 = lane & 15, quad = lane >> 4;

    f32x4 aq[2][4] = {}, ak[2][4] = {}, av[2][4] = {};
    const size_t xb = (size_t)mblk * 262144;
    const size_t qb = (size_t)head * 131072;
    const size_t kbw = (size_t)head * 131072;
    const size_t vbw = (size_t)head * 65536;

    auto stage = [&](int kc, int boff) {
#pragma unroll
        for (int j = 0; j < 4; ++j) {
            int u = j * 256 + tid;
            gl_lds16(Xpk + xb + (size_t)kc * 8192 + u * 8, &lds[boff + u * 8]);
        }
#pragma unroll
        for (int j = 0; j < 2; ++j) {
            int u = j * 256 + tid;
            gl_lds16(Wqpk + qb + (size_t)kc * 4096 + u * 8, &lds[boff + 8192 + u * 8]);
            gl_lds16(Wkpk + kbw + (size_t)kc * 4096 + u * 8, &lds[boff + 12288 + u * 8]);
        }
        gl_lds16(Wvpk + vbw + (size_t)kc * 2048 + tid * 8, &lds[boff + 16384 + tid * 8]);
    };

    auto compute = [&](int boff) {
        bf16x8 ah[2], al8[2];
#pragma unroll
        for (int mt = 0; mt < 2; ++mt) {
            int row = w * 32 + mt * 16 + l15;
            ah[mt] = *(const bf16x8*)&lds[boff + row * 64 + ((quad ^ (row & 7))) * 8];
            al8[mt] = *(const bf16x8*)&lds[boff + row * 64 + (((4 + quad) ^ (row & 7))) * 8];
        }
#pragma unroll
        for (int nt = 0; nt < 4; ++nt) {
            int col = nt * 16 + l15;
            int g_h = (quad ^ (col & 7)) * 8;
            int g_l = ((4 + quad) ^ (col & 7)) * 8;
            bf16x8 bqh = *(const bf16x8*)&lds[boff + 8192 + col * 64 + g_h];
            bf16x8 bql = *(const bf16x8*)&lds[boff + 8192 + col * 64 + g_l];
            bf16x8 bkh = *(const bf16x8*)&lds[boff + 12288 + col * 64 + g_h];
            bf16x8 bkl = *(const bf16x8*)&lds[boff + 12288 + col * 64 + g_l];
            bf16x8 bv = *(const bf16x8*)&lds[boff + 16384 + col * 32 + ((quad ^ (col & 3))) * 8];
#pragma unroll
            for (int mt = 0; mt < 2; ++mt) {
                f32x4 a = aq[mt][nt];
                a = MFMA(ah[mt], bqh, a);
                a = MFMA(ah[mt], bql, a);
                a = MFMA(al8[mt], bqh, a);
                aq[mt][nt] = a;
                f32x4 b = ak[mt][nt];
                b = MFMA(ah[mt], bkh, b);
                b = MFMA(ah[mt], bkl, b);
                b = MFMA(al8[mt], bkh, b);
                ak[mt][nt] = b;
                av[mt][nt] = MFMA(ah[mt], bv, av[mt][nt]);
            }
        }
    };

    stage(0, 0);
#pragma unroll 1
    for (int kc = 0; kc < 32; kc += 2) {
        __syncthreads();  // buf0 (chunk kc) ready
        if (kc + 1 < 32) stage(kc + 1, 18432);
        compute(0);
        __syncthreads();  // buf1 (chunk kc+1) ready
        if (kc + 2 < 32) stage(kc + 2, 0);
        compute(18432);
    }

#pragma unroll
    for (int mt = 0; mt < 2; ++mt) {
        const int rbase = mblk * 128 + w * 32 + mt * 16 + quad * 4;
#pragma unroll
        for (int nt = 0; nt < 4; ++nt) {
            const int col = head * 64 + nt * 16 + l15;
#pragma unroll
            for (int r = 0; r < 4; ++r) {
                size_t a = (size_t)(rbase + r) * D_DIM + col;
                float vq = aq[mt][nt][r];
                unsigned short hq = f2bf(vq);
                Qh[a] = hq;
                Ql[a] = f2bf(vq - bf2f(hq));
                float vk = ak[mt][nt][r];
                unsigned short hk = f2bf(vk);
                Kh[a] = hk;
                Kl[a] = f2bf(vk - bf2f(hk));
            }
            ushort4 vp;
            vp.x = f2bf(av[mt][nt][0]);
            vp.y = f2bf(av[mt][nt][1]);
            vp.z = f2bf(av[mt][nt][2]);
            vp.w = f2bf(av[mt][nt][3]);
            *(ushort4*)(Vt + (size_t)col * (2 * S_LEN) + rbase) = vp;
        }
    }
}

// ---------------------------------------------------------------------------
// attn: flash attention, S^T = K.Q^T.  Block = 128 q-rows (4 waves x 32),
// full 2048-key sweep.  Double-buffered LDS staging (Kh/Kl/V, 24 KB/buf),
// compile-time buffer offsets, one barrier per chunk -> staging hidden.
// Per-lane li partials (epilogue-only reduction); packed bf16 cvt for P.
// grid: dir(2) x head(16) x qblk(16) = 512 blocks
// ---------------------------------------------------------------------------
__global__ __launch_bounds__(256) void attn_kernel(const unsigned short* __restrict__ Qh_,
                                                   const unsigned short* __restrict__ Ql_,
                                                   const unsigned short* __restrict__ Kh_,
                                                   const unsigned short* __restrict__ Kl_,
                                                   const unsigned short* __restrict__ Vt_,
                                                   unsigned short* __restrict__ Oatt) {
    // shorts: buf0 Kh[0,4096) Kl[4096,8192) V[8192,12288); buf1 +12288; P 24576+w*1024
    __shared__ unsigned short lds[28672];
    const int bid = blockIdx.x;
    const int qblk = bid & 15;
    const int head = (bid >> 4) & 15;
    const int dir = bid >> 8;
    const int src_q = dir, src_kv = 1 - dir;

    const int tid = threadIdx.x;
    const int lane = tid & 63;
    const int w = tid >> 6;
    const int l15 = lane & 15, quad = lane >> 4;
    const int q0w = qblk * 128 + w * 32;

    const unsigned short* KhB0 = Kh_ + (size_t)(src_kv * S_LEN) * D_DIM + head * 64;
    const unsigned short* KlB0 = Kl_ + (size_t)(src_kv * S_LEN) * D_DIM + head * 64;
    const unsigned short* Vtp = Vt_ + (size_t)(head * 64) * (2 * S_LEN) + src_kv * S_LEN;

    const int i0 = tid, i1 = 256 + tid;
    const int sr0 = i0 >> 3, sc0 = ((i0 & 7) ^ (sr0 & 7)) * 8;
    const int sr1 = i1 >> 3, sc1 = ((i1 & 7) ^ (sr1 & 7)) * 8;

    auto stage = [&](int k0, int boff) {
        const unsigned short* KhB = KhB0 + (size_t)k0 * D_DIM;
        const unsigned short* KlB = KlB0 + (size_t)k0 * D_DIM;
        const unsigned short* VB = Vtp + k0;
        gl_lds16(KhB + (size_t)sr0 * D_DIM + sc0, &lds[boff + i0 * 8]);
        gl_lds16(KhB + (size_t)sr1 * D_DIM + sc1, &lds[boff + i1 * 8]);
        gl_lds16(KlB + (size_t)sr0 * D_DIM + sc0, &lds[boff + 4096 + i0 * 8]);
        gl_lds16(KlB + (size_t)sr1 * D_DIM + sc1, &lds[boff + 4096 + i1 * 8]);
        gl_lds16(VB + (size_t)sr0 * (2 * S_LEN) + sc0, &lds[boff + 8192 + i0 * 8]);
        gl_lds16(VB + (size_t)sr1 * (2 * S_LEN) + sc1, &lds[boff + 8192 + i1 * 8]);
    };

    // Q fragments (B-operand): B[k=e][n=q], lane n=l15, k=quad*8+j (+c*32)
    bf16x8 qh[2][2], ql[2][2];
#pragma unroll
    for (int mt = 0; mt < 2; ++mt) {
        const size_t qrow =
            (size_t)(src_q * S_LEN + q0w + mt * 16 + l15) * D_DIM + head * 64 + quad * 8;
#pragma unroll
        for (int c = 0; c < 2; ++c) {
            qh[mt][c] = *(const bf16x8*)(Qh_ + qrow + c * 32);
            ql[mt][c] = *(const bf16x8*)(Ql_ + qrow + c * 32);
        }
    }

    f32x4 o[2][4] = {};  // out^T tiles: [mt(q-tile)][et(e-tile)], lane: q=l15, e=quad*4+r
    float mi[2] = {-1e30f, -1e30f};
    float lip[2] = {0.f, 0.f};  // per-lane li partials (this lane's 16 keys/chunk)
    unsigned short* Pw = lds + 24576 + w * 1024;

    auto chunk = [&](int kb) {
        // S^T tiles: sa[mt][kt], keys kt*16+quad*4+r, q = l15 (3-pass split-bf16)
        f32x4 sa[2][4];
#pragma unroll
        for (int kt = 0; kt < 4; ++kt) {
            const int row = kt * 16 + l15;
            const int s0 = (quad ^ (row & 7)) * 8;
            const int s1 = ((4 + quad) ^ (row & 7)) * 8;
            bf16x8 kh0 = *(const bf16x8*)&lds[kb + row * 64 + s0];
            bf16x8 kh1 = *(const bf16x8*)&lds[kb + row * 64 + s1];
            bf16x8 kl0 = *(const bf16x8*)&lds[kb + 4096 + row * 64 + s0];
            bf16x8 kl1 = *(const bf16x8*)&lds[kb + 4096 + row * 64 + s1];
#pragma unroll
            for (int mt = 0; mt < 2; ++mt) {
                f32x4 a = {};
                a = MFMA(kh0, qh[mt][0], a);
                a = MFMA(kh1, qh[mt][1], a);
                a = MFMA(kl0, qh[mt][0], a);
                a = MFMA(kl1, qh[mt][1], a);
                a = MFMA(kh0, ql[mt][0], a);
                a = MFMA(kh1, ql[mt][1], a);
                sa[mt][kt] = a;
            }
        }

        // per m-tile: online softmax (exp2 domain) + PV
#pragma unroll
        for (int mt = 0; mt < 2; ++mt) {
            f32x4 t4 = __builtin_elementwise_max(__builtin_elementwise_max(sa[mt][0], sa[mt][1]),
                                                 __builtin_elementwise_max(sa[mt][2], sa[mt][3]));
            float tm = fmaxf(fmaxf(t4[0], t4[1]), fmaxf(t4[2], t4[3]));
            tm = fmaxf(tm, __shfl_xor(tm, 16, 64));
            tm = fmaxf(tm, __shfl_xor(tm, 32, 64));
            if (__ballot(tm > mi[mt])) {  // rescale only when some row's max rises
                float mn = fmaxf(mi[mt], tm);
                float al = exp2f(mi[mt] - mn);
                mi[mt] = mn;
                lip[mt] *= al;
                const f32x4 alv = {al, al, al, al};
#pragma unroll
                for (int et = 0; et < 4; ++et) o[mt][et] *= alv;
            }
            const float mn = mi[mt];
            const f32x4 mnv = {mn, mn, mn, mn};
            f32x4 rs4 = {};
#pragma unroll
            for (int kt = 0; kt < 4; ++kt) {
                f32x4 p = sa[mt][kt] - mnv;
#pragma unroll
                for (int r = 0; r < 4; ++r) p[r] = exp2f(p[r]);
                rs4 += p;
                uint2 pk;
                pk.x = pack_bf16(p[0], p[1]);
                pk.y = pack_bf16(p[2], p[3]);
                int g = (kt * 2 + (quad >> 1)) ^ (l15 & 7);
                *(uint2*)&Pw[l15 * 64 + g * 8 + (quad & 1) * 4] = pk;
            }
            lip[mt] += (rs4[0] + rs4[1]) + (rs4[2] + rs4[3]);

            // PV: out^T = V^T . P^T  (A = staged V from LDS, B = P^T from LDS)
#pragma unroll
            for (int c = 0; c < 2; ++c) {
                bf16x8 pf = *(const bf16x8*)&Pw[l15 * 64 + (((c * 4 + quad) ^ (l15 & 7)) * 8)];
#pragma unroll
                for (int et = 0; et < 4; ++et) {
                    const int row = et * 16 + l15;
                    const int sl = ((c * 4 + quad) ^ (row & 7)) * 8;
                    bf16x8 vf = *(const bf16x8*)&lds[kb + 8192 + row * 64 + sl];
                    o[mt][et] = MFMA(vf, pf, o[mt][et]);
                }
            }
        }
    };

    stage(0, 0);
#pragma unroll 1
    for (int kd = 0; kd < 32; kd += 2) {
        __syncthreads();  // buf0 (chunk kd) ready
        if (kd + 1 < 32) stage((kd + 1) * 64, 12288);
        chunk(0);
        __syncthreads();  // buf1 (chunk kd+1) ready
        if (kd + 2 < 32) stage((kd + 2) * 64, 0);
        chunk(12288);
    }

    // epilogue: reduce li across the quad group, normalize, store to TILED Oatt
    const size_t obase = (size_t)(dir * 16 + head) * 131072 + (size_t)l15 * 8192;
#pragma unroll
    for (int mt = 0; mt < 2; ++mt) {
        float lq = lip[mt];
        lq += __shfl_xor(lq, 16, 64);
        lq += __shfl_xor(lq, 32, 64);
        float rl = __builtin_amdgcn_rcpf(lq);
        const int rowit = qblk * 8 + w * 2 + mt;
#pragma unroll
        for (int et = 0; et < 4; ++et) {
            int g = ((et * 2 + (quad >> 1)) ^ (rowit & 7)) & 7;
            ushort4 pk;
            pk.x = f2bf(o[mt][et][0] * rl);
            pk.y = f2bf(o[mt][et][1] * rl);
            pk.z = f2bf(o[mt][et][2] * rl);
            pk.w = f2bf(o[mt][et][3] * rl);
            *(ushort4*)(Oatt + obase + (size_t)rowit * 64 + g * 8 + (quad & 1) * 4) = pk;
        }
    }
}

// ---------------------------------------------------------------------------
// oproj: out = view @ Wo, staged-LDS GEMM, double-buffered prefetch.
// grid: mblk(32) x nblk(16) = 512 blocks
// ---------------------------------------------------------------------------
__global__ __launch_bounds__(256) void oproj(const unsigned short* __restrict__ Oatt,
                                             const unsigned short* __restrict__ Wot,
                                             float* __restrict__ out) {
    __shared__ unsigned short lds[24576];  // buf: A 8192 + B 4096; x2
    const int bid = blockIdx.x;
    const int nblk = bid & 15;
    const int mblk = bid >> 4;
    const int tid = threadIdx.x;
    const int lane = tid & 63, w = tid >> 6, l15 = lane & 15, quad = lane >> 4;

    f32x4 acc[2][4] = {};
    const size_t abase = (size_t)mblk * 131072;
    const size_t bbase = (size_t)nblk * 65536;

    auto ostage = [&](int kb, int boff) {
#pragma unroll
        for (int j = 0; j < 4; ++j) {
            int seg = j * 256 + tid;
            gl_lds16(Oatt + abase + (size_t)kb * 8192 + seg * 8, &lds[boff + seg * 8]);
        }
#pragma unroll
        for (int j = 0; j < 2; ++j) {
            int seg = j * 256 + tid;
            gl_lds16(Wot + bbase + (size_t)kb * 4096 + seg * 8, &lds[boff + 8192 + seg * 8]);
        }
    };

    auto compute = [&](int boff) {
#pragma unroll
        for (int ksub = 0; ksub < 2; ++ksub) {
            bf16x8 a[2];
#pragma unroll
            for (int mt = 0; mt < 2; ++mt) {
                int row = w * 32 + mt * 16 + l15;
                a[mt] =
                    *(const bf16x8*)&lds[boff + row * 64 + (((ksub * 4 + quad) ^ (row & 7)) * 8)];
            }
#pragma unroll
            for (int nt = 0; nt < 4; ++nt) {
                int col = nt * 16 + l15;
                bf16x8 b = *(const bf16x8*)&lds[boff + 8192 + col * 64 +
                                                (((ksub * 4 + quad) ^ (col & 7)) * 8)];
#pragma unroll
                for (int mt = 0; mt < 2; ++mt) acc[mt][nt] = MFMA(a[mt], b, acc[mt][nt]);
            }
        }
    };

    ostage(0, 0);
#pragma unroll 1
    for (int kb = 0; kb < 16; kb += 2) {
        __syncthreads();
        if (kb + 1 < 16) ostage(kb + 1, 12288);
        compute(0);
        __syncthreads();
        if (kb + 2 < 16) ostage(kb + 2, 0);
        compute(12288);
    }

#pragma unroll
    for (int mt = 0; mt < 2; ++mt) {
        const int rbase = mblk * 128 + w * 32 + mt * 16 + quad * 4;
#pragma unroll
        for (int nt = 0; nt < 4; ++nt)
#pragma unroll
            for (int r = 0; r < 4; ++r)
                out[(size_t)(rbase + r) * D_DIM + nblk * 64 + nt * 16 + l15] = acc[mt][nt][r];
    }
}

// ---------------------------------------------------------------------------
extern "C" void kernel_launch(void* const* d_in, const int* in_sizes, int n_in, void* d_out,
                              int out_size, void* d_ws, size_t ws_size, hipStream_t stream) {
    const float* GLO = (const float*)d_in[0];
    const float* LOC = (const float*)d_in[1];
    const float* Wq = (const float*)d_in[2];
    const float* Wk = (const float*)d_in[3];
    const float* Wv = (const float*)d_in[4];
    const float* Wo = (const float*)d_in[5];
    float* out = (float*)d_out;

    unsigned short* ws = (unsigned short*)d_ws;
    unsigned short* Xpk = ws + 0;         // 8M shorts
    unsigned short* Wqpk = ws + 8388608;  // 2M
    unsigned short* Wkpk = ws + 10485760;  // 2M
    unsigned short* Wvpk = ws + 12582912;  // 1M
    unsigned short* Wot = ws + 13631488;   // 1M
    unsigned short* Qh = ws + 14680064;
    unsigned short* Ql = ws + 18874368;
    unsigned short* Kh = ws + 23068672;
    unsigned short* Kl = ws + 27262976;
    unsigned short* Vt = ws + 31457280;
    unsigned short* Oatt = ws + 35651584;

    prep<<<32768, 256, 0, stream>>>(GLO, LOC, Wq, Wk, Wv, Wo, Xpk, Wqpk, Wkpk, Wvpk, Wot);
    qkv_proj<<<512, 256, 0, stream>>>(Xpk, Wqpk, Wkpk, Wvpk, Qh, Ql, Kh, Kl, Vt);
    attn_kernel<<<512, 256, 0, stream>>>(Qh, Ql, Kh, Kl, Vt, Oatt);
    oproj<<<512, 256, 0, stream>>>(Oatt, Wot, out);
}

// Round 13
// 247.117 us; speedup vs baseline: 1.2100x; 1.2100x over previous
//
#include <hip/hip_runtime.h>
#include <math.h>

#define S_LEN 2048
#define D_DIM 1024
#define NH 16
#define HD 64

typedef __attribute__((ext_vector_type(8))) short bf16x8;
typedef __attribute__((ext_vector_type(4))) float f32x4;

#define MFMA(a, b, c) __builtin_amdgcn_mfma_f32_16x16x32_bf16((a), (b), (c), 0, 0, 0)

__device__ __forceinline__ unsigned short f2bf(float x) {
    unsigned int u = __float_as_uint(x);
    u = (u + 0x7FFFu + ((u >> 16) & 1u)) >> 16;  // round-to-nearest-even
    return (unsigned short)u;
}
__device__ __forceinline__ float bf2f(unsigned short b) {
    return __uint_as_float(((unsigned int)b) << 16);
}
__device__ __forceinline__ void gl_lds16(const void* g, void* l) {
    __builtin_amdgcn_global_load_lds((const __attribute__((address_space(1))) unsigned int*)g,
                                     (__attribute__((address_space(3))) unsigned int*)l, 16, 0, 0);
}

// packed f32x2 -> bf16x2 (low = a, high = b).
#if defined(__has_builtin)
#if __has_builtin(__builtin_amdgcn_cvt_pk_bf16_f32)
#define HAVE_CVT_PK_BF16 1
#endif
#endif
__device__ __forceinline__ unsigned pack_bf16(float a, float b) {
#ifdef HAVE_CVT_PK_BF16
    auto r = __builtin_amdgcn_cvt_pk_bf16_f32(a, b);
    unsigned u;
    __builtin_memcpy(&u, &r, 4);
    return u;
#else
    unsigned ua = __float_as_uint(a) + 0x8000u;
    unsigned ub = __float_as_uint(b) + 0x8000u;
    return __builtin_amdgcn_perm(ub, ua, 0x07060302u);
#endif
}

// Tiled-swizzled layouts (identity-copy global_load_lds staging, 2-way LDS reads):
//   X/Oatt : [mblk=r>>7][kblk=k>>6][row=r&127][g=((k>>3)&7)^(r&7)][k&7]
//   Wqkv   : [head][kblk=d>>6][col=e][g=((d>>3)&7)^(e&7)][d&7]
//   Wo     : [nblk=n>>6][kblk=k>>6][col=n&63][g=((k>>3)&7)^(n&7)][k&7]

// ---------------------------------------------------------------------------
// prep (GATHER form): one thread = 8 contiguous output shorts (t = idx*8
// falls out of the layout bit-fields), so all writes are coalesced 16 B/lane.
// X reads stay coalesced (8 consecutive floats); the weight transpose
// scatters on the READ side (4-B L2-cached reads) instead of 2-B writes.
// Wq folded scale = 0.125 * log2(e)  -> scores live in exp2 domain.
// (r13 fix: removed the stray placeholder store that zeroed Wqh lanes.)
// grid: 4096 x 256 = 1M threads (X 512K; Wq/Wk/Wv/Wo 128K each)
// ---------------------------------------------------------------------------
__global__ __launch_bounds__(256) void prep(const float* __restrict__ GLO,
                                            const float* __restrict__ LOC,
                                            const float* __restrict__ Wq,
                                            const float* __restrict__ Wk,
                                            const float* __restrict__ Wv,
                                            const float* __restrict__ Wo,
                                            unsigned short* __restrict__ Xh,
                                            unsigned short* __restrict__ Xl,
                                            unsigned short* __restrict__ Wqh,
                                            unsigned short* __restrict__ Wql,
                                            unsigned short* __restrict__ Wkh,
                                            unsigned short* __restrict__ Wkl,
                                            unsigned short* __restrict__ Wvt,
                                            unsigned short* __restrict__ Wot) {
    int idx = blockIdx.x * 256 + threadIdx.x;  // 0 .. 1M-1
    if (idx < (1 << 19)) {
        // X: idx = mblk<<14 | kblk<<10 | row<<3 | gg ; t = idx*8
        int gg = idx & 7;
        int row = (idx >> 3) & 127;
        int kblk = (idx >> 10) & 15;
        int r = (idx >> 14) * 128 + row;  // 0..4095
        int kg = gg ^ (row & 7);
        const float* src = (r & 2048) ? LOC : GLO;
        const float* sp = src + (size_t)(r & 2047) * 1024 + kblk * 64 + kg * 8;
        float4 x0 = *(const float4*)sp;
        float4 x1 = *(const float4*)(sp + 4);
        size_t t = (size_t)idx * 8;
        ushort4 h0, l0, h1, l1;
        h0.x = f2bf(x0.x); l0.x = f2bf(x0.x - bf2f(h0.x));
        h0.y = f2bf(x0.y); l0.y = f2bf(x0.y - bf2f(h0.y));
        h0.z = f2bf(x0.z); l0.z = f2bf(x0.z - bf2f(h0.z));
        h0.w = f2bf(x0.w); l0.w = f2bf(x0.w - bf2f(h0.w));
        h1.x = f2bf(x1.x); l1.x = f2bf(x1.x - bf2f(h1.x));
        h1.y = f2bf(x1.y); l1.y = f2bf(x1.y - bf2f(h1.y));
        h1.z = f2bf(x1.z); l1.z = f2bf(x1.z - bf2f(h1.z));
        h1.w = f2bf(x1.w); l1.w = f2bf(x1.w - bf2f(h1.w));
        *(ushort4*)(Xh + t) = h0;
        *(ushort4*)(Xh + t + 4) = h1;
        *(ushort4*)(Xl + t) = l0;
        *(ushort4*)(Xl + t + 4) = l1;
    } else {
        int idx2 = idx - (1 << 19);
        int sec = idx2 >> 17;    // 0 Wq, 1 Wk, 2 Wv, 3 Wo
        int j = idx2 & 0x1FFFF;  // 128K per section
        size_t t = (size_t)j * 8;
        if (sec < 3) {
            // j = head<<13 | kblk<<9 | e<<3 | gg
            int gg = j & 7;
            int e = (j >> 3) & 63;
            int kblk = (j >> 9) & 15;
            int head = j >> 13;
            int kg = gg ^ (e & 7);
            int d0 = kblk * 64 + kg * 8;
            const float* W = (sec == 0) ? Wq : (sec == 1) ? Wk : Wv;
            const float* wp = W + (size_t)head * 65536 + (size_t)d0 * 64 + e;
            float wv8[8];
#pragma unroll
            for (int i = 0; i < 8; ++i) wv8[i] = wp[i * 64];
            if (sec == 0) {
                ushort4 h0, l0, h1, l1;
#pragma unroll
                for (int i = 0; i < 8; ++i) {
                    float v = wv8[i] * 0.18033688011112042f;  // 0.125 * log2(e)
                    unsigned short hi = f2bf(v);
                    unsigned short lo = f2bf(v - bf2f(hi));
                    if (i < 4) {
                        ((unsigned short*)&h0)[i] = hi;
                        ((unsigned short*)&l0)[i] = lo;
                    } else {
                        ((unsigned short*)&h1)[i - 4] = hi;
                        ((unsigned short*)&l1)[i - 4] = lo;
                    }
                }
                *(ushort4*)(Wqh + t) = h0;
                *(ushort4*)(Wqh + t + 4) = h1;
                *(ushort4*)(Wql + t) = l0;
                *(ushort4*)(Wql + t + 4) = l1;
            } else if (sec == 1) {
                ushort4 h0, l0, h1, l1;
#pragma unroll
                for (int i = 0; i < 8; ++i) {
                    float v = wv8[i];
                    unsigned short hi = f2bf(v);
                    unsigned short lo = f2bf(v - bf2f(hi));
                    if (i < 4) {
                        ((unsigned short*)&h0)[i] = hi;
                        ((unsigned short*)&l0)[i] = lo;
                    } else {
                        ((unsigned short*)&h1)[i - 4] = hi;
                        ((unsigned short*)&l1)[i - 4] = lo;
                    }
                }
                *(ushort4*)(Wkh + t) = h0;
                *(ushort4*)(Wkh + t + 4) = h1;
                *(ushort4*)(Wkl + t) = l0;
                *(ushort4*)(Wkl + t + 4) = l1;
            } else {
                ushort4 v0, v1;
#pragma unroll
                for (int i = 0; i < 8; ++i) {
                    unsigned short b = f2bf(wv8[i]);
                    if (i < 4)
                        ((unsigned short*)&v0)[i] = b;
                    else
                        ((unsigned short*)&v1)[i - 4] = b;
                }
                *(ushort4*)(Wvt + t) = v0;
                *(ushort4*)(Wvt + t + 4) = v1;
            }
        } else {
            // j = nblk<<13 | kblk<<9 | col<<3 | gg
            int gg = j & 7;
            int col = (j >> 3) & 63;
            int kblk = (j >> 9) & 15;
            int nblk = j >> 13;
            int kg = gg ^ (col & 7);
            int k0 = kblk * 64 + kg * 8;
            int n = nblk * 64 + col;
            ushort4 v0, v1;
#pragma unroll
            for (int i = 0; i < 8; ++i) {
                unsigned short b = f2bf(Wo[(size_t)(k0 + i) * 1024 + n]);
                if (i < 4)
                    ((unsigned short*)&v0)[i] = b;
                else
                    ((unsigned short*)&v1)[i - 4] = b;
            }
            *(ushort4*)(Wot + t) = v0;
            *(ushort4*)(Wot + t + 4) = v1;
        }
    }
}

// ---------------------------------------------------------------------------
// qkv_proj: staged-LDS GEMM, 7 MFMA passes share staged A/B.  (round-10
// version: BK=64 single-buffer — qkv is TRAFFIC-bound (~590 MB), so the
// BK=32 double-buffer of round 11 couldn't help and added overhead.)
// grid: mblk(32) x head(16) = 512 blocks
// ---------------------------------------------------------------------------
__global__ __launch_bounds__(256) void qkv_proj(const unsigned short* __restrict__ Xh,
                                                const unsigned short* __restrict__ Xl,
                                                const unsigned short* __restrict__ Wqh,
                                                const unsigned short* __restrict__ Wql,
                                                const unsigned short* __restrict__ Wkh,
                                                const unsigned short* __restrict__ Wkl,
                                                const unsigned short* __restrict__ Wvt,
                                                unsigned short* __restrict__ Qh,
                                                unsigned short* __restrict__ Ql,
                                                unsigned short* __restrict__ Kh,
                                                unsigned short* __restrict__ Kl,
                                                unsigned short* __restrict__ Vt) {
    __shared__ unsigned short lds[36864];
    const int bid = blockIdx.x;
    const int mblk = bid & 31;
    const int head = bid >> 5;
    const int tid = threadIdx.x;
    const int lane = tid & 63;
    const int w = tid >> 6;
    const int l15 = lane & 15, quad = lane >> 4;

    f32x4 aq[2][4] = {}, ak[2][4] = {}, av[2][4] = {};
    const size_t abase0 = (size_t)mblk * 131072;
    const size_t bbase0 = (size_t)head * 65536;

    for (int kb = 0; kb < 16; ++kb) {
        __syncthreads();
        {
            const size_t ab = abase0 + (size_t)kb * 8192;
            const size_t bb = bbase0 + (size_t)kb * 4096;
#pragma unroll
            for (int j = 0; j < 4; ++j) {
                int seg = j * 256 + tid;
                gl_lds16(Xh + ab + seg * 8, &lds[seg * 8]);
                gl_lds16(Xl + ab + seg * 8, &lds[8192 + seg * 8]);
            }
#pragma unroll
            for (int j = 0; j < 2; ++j) {
                int seg = j * 256 + tid;
                gl_lds16(Wqh + bb + seg * 8, &lds[16384 + seg * 8]);
                gl_lds16(Wql + bb + seg * 8, &lds[20480 + seg * 8]);
                gl_lds16(Wkh + bb + seg * 8, &lds[24576 + seg * 8]);
                gl_lds16(Wkl + bb + seg * 8, &lds[28672 + seg * 8]);
                gl_lds16(Wvt + bb + seg * 8, &lds[32768 + seg * 8]);
            }
        }
        __syncthreads();

#pragma unroll
        for (int ksub = 0; ksub < 2; ++ksub) {
            bf16x8 ah[2], al8[2];
#pragma unroll
            for (int mt = 0; mt < 2; ++mt) {
                int row = w * 32 + mt * 16 + l15;
                int g = (ksub * 4 + quad) ^ (row & 7);
                ah[mt] = *(const bf16x8*)&lds[row * 64 + g * 8];
                al8[mt] = *(const bf16x8*)&lds[8192 + row * 64 + g * 8];
            }
#pragma unroll
            for (int nt = 0; nt < 4; ++nt) {
                int col = nt * 16 + l15;
                int o = col * 64 + ((ksub * 4 + quad) ^ (col & 7)) * 8;
                bf16x8 bqh = *(const bf16x8*)&lds[16384 + o];
                bf16x8 bql = *(const bf16x8*)&lds[20480 + o];
                bf16x8 bkh = *(const bf16x8*)&lds[24576 + o];
                bf16x8 bkl = *(const bf16x8*)&lds[28672 + o];
                bf16x8 bv = *(const bf16x8*)&lds[32768 + o];
#pragma unroll
                for (int mt = 0; mt < 2; ++mt) {
                    f32x4 a = aq[mt][nt];
                    a = MFMA(ah[mt], bqh, a);
                    a = MFMA(ah[mt], bql, a);
                    a = MFMA(al8[mt], bqh, a);
                    aq[mt][nt] = a;
                    f32x4 b = ak[mt][nt];
                    b = MFMA(ah[mt], bkh, b);
                    b = MFMA(ah[mt], bkl, b);
                    b = MFMA(al8[mt], bkh, b);
                    ak[mt][nt] = b;
                    av[mt][nt] = MFMA(ah[mt], bv, av[mt][nt]);
                }
            }
        }
    }

#pragma unroll
    for (int mt = 0; mt < 2; ++mt) {
        const int rbase = mblk * 128 + w * 32 + mt * 16 + quad * 4;
#pragma unroll
        for (int nt = 0; nt < 4; ++nt) {
            const int col = head * 64 + nt * 16 + l15;
#pragma unroll
            for (int r = 0; r < 4; ++r) {
                size_t a = (size_t)(rbase + r) * D_DIM + col;
                float vq = aq[mt][nt][r];
                unsigned short hq = f2bf(vq);
                Qh[a] = hq;
                Ql[a] = f2bf(vq - bf2f(hq));
                float vk = ak[mt][nt][r];
                unsigned short hk = f2bf(vk);
                Kh[a] = hk;
                Kl[a] = f2bf(vk - bf2f(hk));
            }
            ushort4 vp;
            vp.x = f2bf(av[mt][nt][0]);
            vp.y = f2bf(av[mt][nt][1]);
            vp.z = f2bf(av[mt][nt][2]);
            vp.w = f2bf(av[mt][nt][3]);
            *(ushort4*)(Vt + (size_t)col * (2 * S_LEN) + rbase) = vp;
        }
    }
}

// ---------------------------------------------------------------------------
// attn: flash attention, S^T = K.Q^T.  Block = 128 q-rows (4 waves x 32),
// full 2048-key sweep.  Double-buffered LDS staging (Kh/Kl/V, 24 KB/buf),
// compile-time buffer offsets, one barrier per chunk -> staging hidden.
// Per-lane li partials (epilogue-only reduction); packed bf16 cvt for P.
// grid: dir(2) x head(16) x qblk(16) = 512 blocks
// ---------------------------------------------------------------------------
__global__ __launch_bounds__(256) void attn_kernel(const unsigned short* __restrict__ Qh_,
                                                   const unsigned short* __restrict__ Ql_,
                                                   const unsigned short* __restrict__ Kh_,
                                                   const unsigned short* __restrict__ Kl_,
                                                   const unsigned short* __restrict__ Vt_,
                                                   unsigned short* __restrict__ Oatt) {
    // shorts: buf0 Kh[0,4096) Kl[4096,8192) V[8192,12288); buf1 +12288; P 24576+w*1024
    __shared__ unsigned short lds[28672];
    const int bid = blockIdx.x;
    const int qblk = bid & 15;
    const int head = (bid >> 4) & 15;
    const int dir = bid >> 8;
    const int src_q = dir, src_kv = 1 - dir;

    const int tid = threadIdx.x;
    const int lane = tid & 63;
    const int w = tid >> 6;
    const int l15 = lane & 15, quad = lane >> 4;
    const int q0w = qblk * 128 + w * 32;

    const unsigned short* KhB0 = Kh_ + (size_t)(src_kv * S_LEN) * D_DIM + head * 64;
    const unsigned short* KlB0 = Kl_ + (size_t)(src_kv * S_LEN) * D_DIM + head * 64;
    const unsigned short* Vtp = Vt_ + (size_t)(head * 64) * (2 * S_LEN) + src_kv * S_LEN;

    const int i0 = tid, i1 = 256 + tid;
    const int sr0 = i0 >> 3, sc0 = ((i0 & 7) ^ (sr0 & 7)) * 8;
    const int sr1 = i1 >> 3, sc1 = ((i1 & 7) ^ (sr1 & 7)) * 8;

    auto stage = [&](int k0, int boff) {
        const unsigned short* KhB = KhB0 + (size_t)k0 * D_DIM;
        const unsigned short* KlB = KlB0 + (size_t)k0 * D_DIM;
        const unsigned short* VB = Vtp + k0;
        gl_lds16(KhB + (size_t)sr0 * D_DIM + sc0, &lds[boff + i0 * 8]);
        gl_lds16(KhB + (size_t)sr1 * D_DIM + sc1, &lds[boff + i1 * 8]);
        gl_lds16(KlB + (size_t)sr0 * D_DIM + sc0, &lds[boff + 4096 + i0 * 8]);
        gl_lds16(KlB + (size_t)sr1 * D_DIM + sc1, &lds[boff + 4096 + i1 * 8]);
        gl_lds16(VB + (size_t)sr0 * (2 * S_LEN) + sc0, &lds[boff + 8192 + i0 * 8]);
        gl_lds16(VB + (size_t)sr1 * (2 * S_LEN) + sc1, &lds[boff + 8192 + i1 * 8]);
    };

    // Q fragments (B-operand): B[k=e][n=q], lane n=l15, k=quad*8+j (+c*32)
    bf16x8 qh[2][2], ql[2][2];
#pragma unroll
    for (int mt = 0; mt < 2; ++mt) {
        const size_t qrow =
            (size_t)(src_q * S_LEN + q0w + mt * 16 + l15) * D_DIM + head * 64 + quad * 8;
#pragma unroll
        for (int c = 0; c < 2; ++c) {
            qh[mt][c] = *(const bf16x8*)(Qh_ + qrow + c * 32);
            ql[mt][c] = *(const bf16x8*)(Ql_ + qrow + c * 32);
        }
    }

    f32x4 o[2][4] = {};  // out^T tiles: [mt(q-tile)][et(e-tile)], lane: q=l15, e=quad*4+r
    float mi[2] = {-1e30f, -1e30f};
    float lip[2] = {0.f, 0.f};  // per-lane li partials (this lane's 16 keys/chunk)
    unsigned short* Pw = lds + 24576 + w * 1024;

    auto chunk = [&](int kb) {
        // S^T tiles: sa[mt][kt], keys kt*16+quad*4+r, q = l15 (3-pass split-bf16)
        f32x4 sa[2][4];
#pragma unroll
        for (int kt = 0; kt < 4; ++kt) {
            const int row = kt * 16 + l15;
            const int s0 = (quad ^ (row & 7)) * 8;
            const int s1 = ((4 + quad) ^ (row & 7)) * 8;
            bf16x8 kh0 = *(const bf16x8*)&lds[kb + row * 64 + s0];
            bf16x8 kh1 = *(const bf16x8*)&lds[kb + row * 64 + s1];
            bf16x8 kl0 = *(const bf16x8*)&lds[kb + 4096 + row * 64 + s0];
            bf16x8 kl1 = *(const bf16x8*)&lds[kb + 4096 + row * 64 + s1];
#pragma unroll
            for (int mt = 0; mt < 2; ++mt) {
                f32x4 a = {};
                a = MFMA(kh0, qh[mt][0], a);
                a = MFMA(kh1, qh[mt][1], a);
                a = MFMA(kl0, qh[mt][0], a);
                a = MFMA(kl1, qh[mt][1], a);
                a = MFMA(kh0, ql[mt][0], a);
                a = MFMA(kh1, ql[mt][1], a);
                sa[mt][kt] = a;
            }
        }

        // per m-tile: online softmax (exp2 domain) + PV
#pragma unroll
        for (int mt = 0; mt < 2; ++mt) {
            f32x4 t4 = __builtin_elementwise_max(__builtin_elementwise_max(sa[mt][0], sa[mt][1]),
                                                 __builtin_elementwise_max(sa[mt][2], sa[mt][3]));
            float tm = fmaxf(fmaxf(t4[0], t4[1]), fmaxf(t4[2], t4[3]));
            tm = fmaxf(tm, __shfl_xor(tm, 16, 64));
            tm = fmaxf(tm, __shfl_xor(tm, 32, 64));
            if (__ballot(tm > mi[mt])) {  // rescale only when some row's max rises
                float mn = fmaxf(mi[mt], tm);
                float al = exp2f(mi[mt] - mn);
                mi[mt] = mn;
                lip[mt] *= al;
                const f32x4 alv = {al, al, al, al};
#pragma unroll
                for (int et = 0; et < 4; ++et) o[mt][et] *= alv;
            }
            const float mn = mi[mt];
            const f32x4 mnv = {mn, mn, mn, mn};
            f32x4 rs4 = {};
#pragma unroll
            for (int kt = 0; kt < 4; ++kt) {
                f32x4 p = sa[mt][kt] - mnv;
#pragma unroll
                for (int r = 0; r < 4; ++r) p[r] = exp2f(p[r]);
                rs4 += p;
                uint2 pk;
                pk.x = pack_bf16(p[0], p[1]);
                pk.y = pack_bf16(p[2], p[3]);
                int g = (kt * 2 + (quad >> 1)) ^ (l15 & 7);
                *(uint2*)&Pw[l15 * 64 + g * 8 + (quad & 1) * 4] = pk;
            }
            lip[mt] += (rs4[0] + rs4[1]) + (rs4[2] + rs4[3]);

            // PV: out^T = V^T . P^T  (A = staged V from LDS, B = P^T from LDS)
#pragma unroll
            for (int c = 0; c < 2; ++c) {
                bf16x8 pf = *(const bf16x8*)&Pw[l15 * 64 + (((c * 4 + quad) ^ (l15 & 7)) * 8)];
#pragma unroll
                for (int et = 0; et < 4; ++et) {
                    const int row = et * 16 + l15;
                    const int sl = ((c * 4 + quad) ^ (row & 7)) * 8;
                    bf16x8 vf = *(const bf16x8*)&lds[kb + 8192 + row * 64 + sl];
                    o[mt][et] = MFMA(vf, pf, o[mt][et]);
                }
            }
        }
    };

    stage(0, 0);
#pragma unroll 1
    for (int kd = 0; kd < 32; kd += 2) {
        __syncthreads();  // buf0 (chunk kd) ready
        if (kd + 1 < 32) stage((kd + 1) * 64, 12288);
        chunk(0);
        __syncthreads();  // buf1 (chunk kd+1) ready
        if (kd + 2 < 32) stage((kd + 2) * 64, 0);
        chunk(12288);
    }

    // epilogue: reduce li across the quad group, normalize, store to TILED Oatt
    const size_t obase = (size_t)(dir * 16 + head) * 131072 + (size_t)l15 * 8192;
#pragma unroll
    for (int mt = 0; mt < 2; ++mt) {
        float lq = lip[mt];
        lq += __shfl_xor(lq, 16, 64);
        lq += __shfl_xor(lq, 32, 64);
        float rl = __builtin_amdgcn_rcpf(lq);
        const int rowit = qblk * 8 + w * 2 + mt;
#pragma unroll
        for (int et = 0; et < 4; ++et) {
            int g = ((et * 2 + (quad >> 1)) ^ (rowit & 7)) & 7;
            ushort4 pk;
            pk.x = f2bf(o[mt][et][0] * rl);
            pk.y = f2bf(o[mt][et][1] * rl);
            pk.z = f2bf(o[mt][et][2] * rl);
            pk.w = f2bf(o[mt][et][3] * rl);
            *(ushort4*)(Oatt + obase + (size_t)rowit * 64 + g * 8 + (quad & 1) * 4) = pk;
        }
    }
}

// ---------------------------------------------------------------------------
// oproj: out = view @ Wo, staged-LDS GEMM, double-buffered prefetch.
// grid: mblk(32) x nblk(16) = 512 blocks
// ---------------------------------------------------------------------------
__global__ __launch_bounds__(256) void oproj(const unsigned short* __restrict__ Oatt,
                                             const unsigned short* __restrict__ Wot,
                                             float* __restrict__ out) {
    __shared__ unsigned short lds[24576];  // buf: A 8192 + B 4096; x2
    const int bid = blockIdx.x;
    const int nblk = bid & 15;
    const int mblk = bid >> 4;
    const int tid = threadIdx.x;
    const int lane = tid & 63, w = tid >> 6, l15 = lane & 15, quad = lane >> 4;

    f32x4 acc[2][4] = {};
    const size_t abase = (size_t)mblk * 131072;
    const size_t bbase = (size_t)nblk * 65536;

    auto ostage = [&](int kb, int boff) {
#pragma unroll
        for (int j = 0; j < 4; ++j) {
            int seg = j * 256 + tid;
            gl_lds16(Oatt + abase + (size_t)kb * 8192 + seg * 8, &lds[boff + seg * 8]);
        }
#pragma unroll
        for (int j = 0; j < 2; ++j) {
            int seg = j * 256 + tid;
            gl_lds16(Wot + bbase + (size_t)kb * 4096 + seg * 8, &lds[boff + 8192 + seg * 8]);
        }
    };

    auto compute = [&](int boff) {
#pragma unroll
        for (int ksub = 0; ksub < 2; ++ksub) {
            bf16x8 a[2];
#pragma unroll
            for (int mt = 0; mt < 2; ++mt) {
                int row = w * 32 + mt * 16 + l15;
                a[mt] =
                    *(const bf16x8*)&lds[boff + row * 64 + (((ksub * 4 + quad) ^ (row & 7)) * 8)];
            }
#pragma unroll
            for (int nt = 0; nt < 4; ++nt) {
                int col = nt * 16 + l15;
                bf16x8 b = *(const bf16x8*)&lds[boff + 8192 + col * 64 +
                                                (((ksub * 4 + quad) ^ (col & 7)) * 8)];
#pragma unroll
                for (int mt = 0; mt < 2; ++mt) acc[mt][nt] = MFMA(a[mt], b, acc[mt][nt]);
            }
        }
    };

    ostage(0, 0);
#pragma unroll 1
    for (int kb = 0; kb < 16; kb += 2) {
        __syncthreads();
        if (kb + 1 < 16) ostage(kb + 1, 12288);
        compute(0);
        __syncthreads();
        if (kb + 2 < 16) ostage(kb + 2, 0);
        compute(12288);
    }

#pragma unroll
    for (int mt = 0; mt < 2; ++mt) {
        const int rbase = mblk * 128 + w * 32 + mt * 16 + quad * 4;
#pragma unroll
        for (int nt = 0; nt < 4; ++nt)
#pragma unroll
            for (int r = 0; r < 4; ++r)
                out[(size_t)(rbase + r) * D_DIM + nblk * 64 + nt * 16 + l15] = acc[mt][nt][r];
    }
}

// ---------------------------------------------------------------------------
extern "C" void kernel_launch(void* const* d_in, const int* in_sizes, int n_in, void* d_out,
                              int out_size, void* d_ws, size_t ws_size, hipStream_t stream) {
    const float* GLO = (const float*)d_in[0];
    const float* LOC = (const float*)d_in[1];
    const float* Wq = (const float*)d_in[2];
    const float* Wk = (const float*)d_in[3];
    const float* Wv = (const float*)d_in[4];
    const float* Wo = (const float*)d_in[5];
    float* out = (float*)d_out;

    unsigned short* ws = (unsigned short*)d_ws;
    unsigned short* Xh = ws + 0;
    unsigned short* Xl = ws + 4194304;
    unsigned short* Wqh = ws + 8388608;
    unsigned short* Wql = ws + 9437184;
    unsigned short* Wkh = ws + 10485760;
    unsigned short* Wkl = ws + 11534336;
    unsigned short* Wvt = ws + 12582912;
    unsigned short* Wot = ws + 13631488;
    unsigned short* Qh = ws + 14680064;
    unsigned short* Ql = ws + 18874368;
    unsigned short* Kh = ws + 23068672;
    unsigned short* Kl = ws + 27262976;
    unsigned short* Vt = ws + 31457280;
    unsigned short* Oatt = ws + 35651584;

    prep<<<4096, 256, 0, stream>>>(GLO, LOC, Wq, Wk, Wv, Wo, Xh, Xl, Wqh, Wql, Wkh, Wkl, Wvt, Wot);
    qkv_proj<<<512, 256, 0, stream>>>(Xh, Xl, Wqh, Wql, Wkh, Wkl, Wvt, Qh, Ql, Kh, Kl, Vt);
    attn_kernel<<<512, 256, 0, stream>>>(Qh, Ql, Kh, Kl, Vt, Oatt);
    oproj<<<512, 256, 0, stream>>>(Oatt, Wot, out);
}